// Round 1
// 379.846 us; speedup vs baseline: 1.0607x; 1.0607x over previous
//
#include <hip/hip_runtime.h>

typedef __attribute__((ext_vector_type(8))) short short8;
typedef __attribute__((ext_vector_type(4))) float f32x4;
typedef __attribute__((ext_vector_type(8))) unsigned short u16x8;

// sizes (fixed by the problem)
#define BOOKS 8
#define NSAMP 1024
#define OUTF  4096
#define KDIM  256
#define OUT2_OFF 33554432ull   // elements in out1 = 1024*8*4096 (fp32 elements)
#define OUT3_OFF 67108864ull

__device__ __forceinline__ unsigned short f2bf(float f) {
  unsigned int u = __float_as_uint(f);
  u += 0x7fffu + ((u >> 16) & 1u);   // round-to-nearest-even
  return (unsigned short)(u >> 16);
}
__device__ __forceinline__ float b2f(unsigned short u) {
  return __uint_as_float((unsigned)u << 16);
}

__device__ __forceinline__ float wave_sum(float v) {
  #pragma unroll
  for (int off = 32; off; off >>= 1) v += __shfl_xor(v, off, 64);
  return v;
}
// 16-lane-group reductions (for MFMA C-layout rows: col = lane&15)
__device__ __forceinline__ float qsum(float v) {
  #pragma unroll
  for (int off = 1; off < 16; off <<= 1) v += __shfl_xor(v, off, 64);
  return v;
}
__device__ __forceinline__ float qmax(float v) {
  #pragma unroll
  for (int off = 1; off < 16; off <<= 1) v = fmaxf(v, __shfl_xor(v, off, 64));
  return v;
}

// async global->LDS, 16B per lane. LDS dest must be wave-uniform base + lane*16.
__device__ __forceinline__ void gll16(const void* g, void* l) {
  __builtin_amdgcn_global_load_lds((const __attribute__((address_space(1))) void*)g,
                                   (__attribute__((address_space(3))) void*)l,
                                   16, 0, 0);
}

// ---- prep: normalize weight rows -> wn bf16 [8][4096][256] (N x K, K contiguous)
__global__ __launch_bounds__(256) void wnorm_kernel(const float* __restrict__ w,
                                                    unsigned short* __restrict__ wn) {
  int row  = blockIdx.x * 4 + (threadIdx.x >> 6);   // 0..32767
  int lane = threadIdx.x & 63;
  float4 v = ((const float4*)(w + (size_t)row * KDIM))[lane];
  float ss = wave_sum(v.x*v.x + v.y*v.y + v.z*v.z + v.w*v.w);
  float inv = 1.f / fmaxf(sqrtf(ss), 1e-12f);
  ushort4 o;
  o.x = f2bf(v.x*inv); o.y = f2bf(v.y*inv); o.z = f2bf(v.z*inv); o.w = f2bf(v.w*inv);
  *(ushort4*)(wn + (size_t)row * KDIM + lane * 4) = o;
}

// ---- prep: mlp transpose+cast -> mlpT[b][w][d], codebooks cast -> cbb[b][d][w]
__global__ __launch_bounds__(256) void prep_small_kernel(const float* __restrict__ mlp,
                                                         const float* __restrict__ cb,
                                                         unsigned short* __restrict__ mlpT,
                                                         unsigned short* __restrict__ cbb) {
  int blk = blockIdx.x;            // b*256 + d
  int b = blk >> 8, d = blk & 255;
  int w = threadIdx.x;
  size_t src = ((size_t)(b * 256 + d)) * 256 + w;
  cbb[src] = f2bf(cb[src]);
  mlpT[((size_t)b * 256 + w) * 256 + d] = f2bf(mlp[src]);
}

// ---- prep: x raw bf16 [b][i][d] and xn bf16 into An rows 0..1023 per book
__global__ __launch_bounds__(256) void xprep_kernel(const float* __restrict__ input,
                                                    unsigned short* __restrict__ Xb,
                                                    unsigned short* __restrict__ An) {
  int id = blockIdx.x * 4 + (threadIdx.x >> 6);   // b*1024 + i
  int b = id >> 10, i = id & 1023;
  int lane = threadIdx.x & 63;
  float4 v = ((const float4*)(input + (size_t)i * 2048 + b * 256))[lane];
  float ss = wave_sum(v.x*v.x + v.y*v.y + v.z*v.z + v.w*v.w);
  float inv = 1.f / fmaxf(sqrtf(ss), 1e-12f);
  ushort4 r;
  r.x = f2bf(v.x); r.y = f2bf(v.y); r.z = f2bf(v.z); r.w = f2bf(v.w);
  *(ushort4*)(Xb + (size_t)id * KDIM + lane * 4) = r;
  ushort4 n;
  n.x = f2bf(v.x*inv); n.y = f2bf(v.y*inv); n.z = f2bf(v.z*inv); n.w = f2bf(v.w*inv);
  *(ushort4*)(An + ((size_t)b * 2048 + i) * KDIM + lane * 4) = n;
}

// ---- fused mid-chain: logits GEMM -> softmax -> out3 -> s GEMM -> s-norm -> An
// one block per (book, 64-row tile): grid = 8*16 = 128, 4 waves.
// wave wv owns rows wv*16..wv*16+15; all 256 cols (16 col-frags in acc).
// xc / sn handed through lX with XOR swizzle (row stride 512B is 16-way conflict
// unswizzled; byte ^= (row&7)<<4 makes the 16-lane b128 read conflict-free).
__global__ __launch_bounds__(256) void mid_kernel(const unsigned short* __restrict__ Xb,
                                                  const unsigned short* __restrict__ mlpT,
                                                  const unsigned short* __restrict__ cbb,
                                                  unsigned short* __restrict__ An,
                                                  float* __restrict__ out3) {
  __shared__ __align__(16) unsigned short lA[64 * 32];     // 4 KB  (x tile)
  __shared__ __align__(16) unsigned short lB[256 * 32];    // 16 KB (B k-slice)
  __shared__ __align__(16) unsigned short lX[64 * 256];    // 32 KB (xc, then sn)

  const int b  = blockIdx.x >> 4;
  const int m0 = (blockIdx.x & 15) * 64;
  const int tid  = threadIdx.x;
  const int wv   = tid >> 6;
  const int lane = tid & 63;
  const int r16  = lane & 15;
  const int q    = lane >> 4;

  const unsigned short* Ab = Xb   + ((size_t)b * NSAMP + m0) * KDIM;
  const unsigned short* Bm = mlpT + (size_t)b * 256 * KDIM;
  const unsigned short* Bc = cbb  + (size_t)b * 256 * KDIM;

  f32x4 acc[16];
  #pragma unroll
  for (int j = 0; j < 16; ++j) acc[j] = (f32x4){0.f, 0.f, 0.f, 0.f};

  // ---------- GEMM1: logits = x @ mlp  (acc[j][r]: row=q*4+r, col=j*16+r16) ----
  for (int k0 = 0; k0 < KDIM; k0 += 32) {
    __syncthreads();                       // prev-iter LDS readers done
    { int row = tid >> 2, ko = (tid & 3) * 8;
      gll16(Ab + (size_t)row * KDIM + k0 + ko, &lA[tid * 8]); }
    #pragma unroll
    for (int c = 0; c < 4; ++c) {
      int idx = c * 256 + tid;
      int row = idx >> 2, ko = (idx & 3) * 8;
      gll16(Bm + (size_t)row * KDIM + k0 + ko, &lB[idx * 8]);
    }
    __syncthreads();                       // compiler drains vmcnt(0) before barrier
    short8 af = *(const short8*)(lA + (wv * 16 + r16) * 32 + q * 8);
    #pragma unroll
    for (int j = 0; j < 16; ++j) {
      short8 bf = *(const short8*)(lB + (j * 16 + r16) * 32 + q * 8);
      acc[j] = __builtin_amdgcn_mfma_f32_16x16x32_bf16(af, bf, acc[j], 0, 0, 0);
    }
  }

  // ---------- softmax over 256 words per row; xc bf16 -> lX (swizzled) --------
  #pragma unroll
  for (int r = 0; r < 4; ++r) {
    float mx = acc[0][r];
    #pragma unroll
    for (int j = 1; j < 16; ++j) mx = fmaxf(mx, acc[j][r]);
    mx = qmax(mx);
    float s = 0.f;
    #pragma unroll
    for (int j = 0; j < 16; ++j) { float e = __expf(acc[j][r] - mx); acc[j][r] = e; s += e; }
    s = qsum(s);
    float inv = 1.f / s;
    int row = wv * 16 + q * 4 + r;
    unsigned rb  = (unsigned)row * 512;
    unsigned msk = ((unsigned)(row & 7)) << 4;
    #pragma unroll
    for (int j = 0; j < 16; ++j) {
      unsigned byte = (rb + (unsigned)(j * 16 + r16) * 2) ^ msk;
      *(unsigned short*)((char*)lX + byte) = f2bf(acc[j][r] * inv);
    }
  }
  __syncthreads();                         // xc visible to all waves

  // ---------- out3 fp32, coalesced from lX ------------------------------------
  #pragma unroll
  for (int p = 0; p < 8; ++p) {
    int chunk = p * 256 + tid;             // 2048 chunks of 8 elems
    int row = chunk >> 5;
    int c8  = (chunk & 31) * 8;
    unsigned byte = ((unsigned)(row * 512 + c8 * 2)) ^ (((unsigned)(row & 7)) << 4);
    u16x8 v = *(const u16x8*)((char*)lX + byte);
    size_t o = ((size_t)(m0 + row) * 8 + b) * 256 + c8;
    float4 f0 = make_float4(b2f(v[0]), b2f(v[1]), b2f(v[2]), b2f(v[3]));
    float4 f1 = make_float4(b2f(v[4]), b2f(v[5]), b2f(v[6]), b2f(v[7]));
    *(float4*)(out3 + o)     = f0;
    *(float4*)(out3 + o + 4) = f1;
  }

  // ---------- GEMM2: s = xc @ cb^T  (A from lX, swizzled reads) ---------------
  #pragma unroll
  for (int j = 0; j < 16; ++j) acc[j] = (f32x4){0.f, 0.f, 0.f, 0.f};
  for (int k0 = 0; k0 < KDIM; k0 += 32) {
    __syncthreads();                       // prev-iter lB readers done
    #pragma unroll
    for (int c = 0; c < 4; ++c) {
      int idx = c * 256 + tid;
      int row = idx >> 2, ko = (idx & 3) * 8;
      gll16(Bc + (size_t)row * KDIM + k0 + ko, &lB[idx * 8]);
    }
    __syncthreads();
    int arow = wv * 16 + r16;
    unsigned abyte = ((unsigned)(arow * 512 + (k0 + q * 8) * 2)) ^ (((unsigned)(arow & 7)) << 4);
    short8 af = *(const short8*)((char*)lX + abyte);
    #pragma unroll
    for (int j = 0; j < 16; ++j) {
      short8 bf = *(const short8*)(lB + (j * 16 + r16) * 32 + q * 8);
      acc[j] = __builtin_amdgcn_mfma_f32_16x16x32_bf16(af, bf, acc[j], 0, 0, 0);
    }
  }

  // ---------- s-normalize in-register; sn bf16 -> lX; coalesced An store ------
  #pragma unroll
  for (int r = 0; r < 4; ++r) {
    float ss = 0.f;
    #pragma unroll
    for (int j = 0; j < 16; ++j) ss += acc[j][r] * acc[j][r];
    ss = qsum(ss);
    float iv = 1.f / fmaxf(sqrtf(ss), 1e-12f);
    int row = wv * 16 + q * 4 + r;
    unsigned rb  = (unsigned)row * 512;
    unsigned msk = ((unsigned)(row & 7)) << 4;
    #pragma unroll
    for (int j = 0; j < 16; ++j) {
      unsigned byte = (rb + (unsigned)(j * 16 + r16) * 2) ^ msk;
      *(unsigned short*)((char*)lX + byte) = f2bf(acc[j][r] * iv);
    }
  }
  __syncthreads();                         // sn visible to all waves
  #pragma unroll
  for (int p = 0; p < 8; ++p) {
    int chunk = p * 256 + tid;
    int row = chunk >> 5;
    int c8  = (chunk & 31) * 8;
    unsigned byte = ((unsigned)(row * 512 + c8 * 2)) ^ (((unsigned)(row & 7)) << 4);
    u16x8 v = *(const u16x8*)((char*)lX + byte);
    *(u16x8*)(An + ((size_t)b * 2048 + 1024 + m0 + row) * KDIM + c8) = v;
  }
}

// ---- big fused GEMM: [xn; sn] (2048xK) @ wn^T (4096xK), global_load_lds staging,
// fused epilogue (clip, *30, -15 at label col) -> fp32 out1/out2 interleaved layout.
__global__ __launch_bounds__(256) void big_gemm_kernel(const unsigned short* __restrict__ A,
                                                       const unsigned short* __restrict__ B,
                                                       float* __restrict__ Cf,
                                                       const int* __restrict__ label) {
  __shared__ __align__(16) unsigned short lA[128 * 32];
  __shared__ __align__(16) unsigned short lB[128 * 32];

  const int b  = blockIdx.z;
  const int m0 = blockIdx.y * 128;
  const int n0 = blockIdx.x * 128;
  const int tid  = threadIdx.x;
  const int wid  = tid >> 6;
  const int lane = tid & 63;
  const int wm = wid & 1, wn = wid >> 1;
  const int r16 = lane & 15;
  const int q   = lane >> 4;

  const unsigned short* Ab = A + (size_t)b * 2048 * KDIM;
  const unsigned short* Bb = B + (size_t)b * OUTF * KDIM;

  f32x4 acc[4][4];
  #pragma unroll
  for (int i = 0; i < 4; ++i)
    #pragma unroll
    for (int j = 0; j < 4; ++j) acc[i][j] = (f32x4){0.f, 0.f, 0.f, 0.f};

  for (int k0 = 0; k0 < KDIM; k0 += 32) {
    __syncthreads();                       // prev-iter LDS readers done
    #pragma unroll
    for (int c = 0; c < 2; ++c) {
      int idx = c * 256 + tid;
      int row = idx >> 2, ko = (idx & 3) * 8;
      gll16(Ab + (size_t)(m0 + row) * KDIM + k0 + ko, &lA[idx * 8]);
      gll16(Bb + (size_t)(n0 + row) * KDIM + k0 + ko, &lB[idx * 8]);
    }
    __syncthreads();                       // vmcnt(0) drained before barrier

    short8 af[4], bfr[4];
    #pragma unroll
    for (int f = 0; f < 4; ++f) {
      af[f]  = *(const short8*)(lA + (wm * 64 + f * 16 + r16) * 32 + q * 8);
      bfr[f] = *(const short8*)(lB + (wn * 64 + f * 16 + r16) * 32 + q * 8);
    }
    #pragma unroll
    for (int i = 0; i < 4; ++i)
      #pragma unroll
      for (int j = 0; j < 4; ++j)
        acc[i][j] = __builtin_amdgcn_mfma_f32_16x16x32_bf16(af[i], bfr[j], acc[i][j], 0, 0, 0);
  }

  // fused epilogue, direct fp32 stores to out[(row>>10)?out2:out1][(i,b,col)]
  #pragma unroll
  for (int i = 0; i < 4; ++i) {
    int row0 = m0 + wm * 64 + i * 16 + q * 4;
    #pragma unroll
    for (int r = 0; r < 4; ++r) {
      int row = row0 + r;                 // 0..2047 within book
      int gi  = row & 1023;               // sample index
      int lb  = label[gi];
      size_t base = (size_t)(row >> 10) * OUT2_OFF + ((size_t)gi * 8 + b) * OUTF;
      #pragma unroll
      for (int j = 0; j < 4; ++j) {
        int col = n0 + wn * 64 + j * 16 + r16;
        float v = fminf(fmaxf(acc[i][j][r], -1.f), 1.f) * 30.f;
        if (col == lb) v -= 15.f;
        Cf[base + col] = v;
      }
    }
  }
}

extern "C" void kernel_launch(void* const* d_in, const int* in_sizes, int n_in,
                              void* d_out, int out_size, void* d_ws, size_t ws_size,
                              hipStream_t stream) {
  const float* input  = (const float*)d_in[0];
  const int*   label  = (const int*)d_in[1];
  const float* weight = (const float*)d_in[2];
  const float* mlp    = (const float*)d_in[3];
  const float* cb     = (const float*)d_in[4];
  float* out = (float*)d_out;   // fp32: reference output dtype is float32

  // d_ws: only wn + An (24 MB total)
  unsigned short* wn = (unsigned short*)d_ws;     // 8*4096*256 = 8,388,608 elems (16 MB)
  unsigned short* An = wn + 8388608;              // 8*2048*256 = 4,194,304 elems (8 MB)

  // scratch overlaid on d_out regions written only by the FINAL kernel:
  //   out2 region (134 MB fp32): Xb (raw x bf16), mlpT, cbb — 6 MB
  unsigned short* Xb   = (unsigned short*)(out + OUT2_OFF);    // 2,097,152 bf16 elems
  unsigned short* mlpT = Xb + 2097152;                         //   524,288
  unsigned short* cbb  = mlpT + 524288;                        //   524,288
  float*          out3 = out + OUT3_OFF;

  wnorm_kernel<<<dim3(8192), dim3(256), 0, stream>>>(weight, wn);
  prep_small_kernel<<<dim3(2048), dim3(256), 0, stream>>>(mlp, cb, mlpT, cbb);
  xprep_kernel<<<dim3(2048), dim3(256), 0, stream>>>(input, Xb, An);
  // fused: logits GEMM -> softmax (-> out3) -> s GEMM -> s-norm -> An rows 1024..2047
  mid_kernel<<<dim3(128), dim3(256), 0, stream>>>(Xb, mlpT, cbb, An, out3);
  // big fused GEMM: [xn; sn] (2048xK) @ wn^T (4096xK) + clip/scale/margin epilogue
  big_gemm_kernel<<<dim3(32, 16, 8), dim3(256), 0, stream>>>(An, wn, out, label);
}

// Round 3
// 373.719 us; speedup vs baseline: 1.0781x; 1.0164x over previous
//
#include <hip/hip_runtime.h>

typedef __attribute__((ext_vector_type(8))) short short8;
typedef __attribute__((ext_vector_type(4))) float f32x4;
typedef __attribute__((ext_vector_type(8))) unsigned short u16x8;

// sizes (fixed by the problem)
#define BOOKS 8
#define NSAMP 1024
#define OUTF  4096
#define KDIM  256
#define OUT2_OFF 33554432ull   // elements in out1 = 1024*8*4096 (fp32 elements)
#define OUT3_OFF 67108864ull

__device__ __forceinline__ unsigned short f2bf(float f) {
  unsigned int u = __float_as_uint(f);
  u += 0x7fffu + ((u >> 16) & 1u);   // round-to-nearest-even
  return (unsigned short)(u >> 16);
}
__device__ __forceinline__ float b2f(unsigned short u) {
  return __uint_as_float((unsigned)u << 16);
}

__device__ __forceinline__ float wave_sum(float v) {
  #pragma unroll
  for (int off = 32; off; off >>= 1) v += __shfl_xor(v, off, 64);
  return v;
}
// 16-lane-group reductions (for MFMA C-layout rows: col = lane&15)
__device__ __forceinline__ float qsum(float v) {
  #pragma unroll
  for (int off = 1; off < 16; off <<= 1) v += __shfl_xor(v, off, 64);
  return v;
}
__device__ __forceinline__ float qmax(float v) {
  #pragma unroll
  for (int off = 1; off < 16; off <<= 1) v = fmaxf(v, __shfl_xor(v, off, 64));
  return v;
}

// async global->LDS, 16B per lane. LDS dest must be wave-uniform base + lane*16.
__device__ __forceinline__ void gll16(const void* g, void* l) {
  __builtin_amdgcn_global_load_lds((const __attribute__((address_space(1))) void*)g,
                                   (__attribute__((address_space(3))) void*)l,
                                   16, 0, 0);
}

// ---- merged prep:
//   blocks [0,8192):      wnorm  (weight rows -> wn bf16, NxK K-contig)
//   blocks [8192,10240):  xprep  (x raw bf16 -> Xb, xn bf16 -> An rows 0..1023)
//   blocks [10240,10368): mlp transpose (LDS-tiled, coalesced both sides) + cb cast
__global__ __launch_bounds__(256) void prep_kernel(const float* __restrict__ input,
                                                   const float* __restrict__ weight,
                                                   const float* __restrict__ mlp,
                                                   const float* __restrict__ cb,
                                                   unsigned short* __restrict__ wn,
                                                   unsigned short* __restrict__ Xb,
                                                   unsigned short* __restrict__ An,
                                                   unsigned short* __restrict__ mlpT,
                                                   unsigned short* __restrict__ cbb) {
  __shared__ float lt[64][65];   // padded f32 transpose tile (2-way bank alias = free)
  const int blk = blockIdx.x;
  const int tid = threadIdx.x;

  if (blk < 8192) {
    // ---- wnorm
    int row  = blk * 4 + (tid >> 6);
    int lane = tid & 63;
    float4 v = ((const float4*)(weight + (size_t)row * KDIM))[lane];
    float ss = wave_sum(v.x*v.x + v.y*v.y + v.z*v.z + v.w*v.w);
    float inv = 1.f / fmaxf(sqrtf(ss), 1e-12f);
    ushort4 o;
    o.x = f2bf(v.x*inv); o.y = f2bf(v.y*inv); o.z = f2bf(v.z*inv); o.w = f2bf(v.w*inv);
    *(ushort4*)(wn + (size_t)row * KDIM + lane * 4) = o;
  } else if (blk < 10240) {
    // ---- xprep
    int id = (blk - 8192) * 4 + (tid >> 6);   // b*1024 + i
    int b = id >> 10, i = id & 1023;
    int lane = tid & 63;
    float4 v = ((const float4*)(input + (size_t)i * 2048 + b * 256))[lane];
    float ss = wave_sum(v.x*v.x + v.y*v.y + v.z*v.z + v.w*v.w);
    float inv = 1.f / fmaxf(sqrtf(ss), 1e-12f);
    ushort4 r;
    r.x = f2bf(v.x); r.y = f2bf(v.y); r.z = f2bf(v.z); r.w = f2bf(v.w);
    *(ushort4*)(Xb + (size_t)id * KDIM + lane * 4) = r;
    ushort4 n;
    n.x = f2bf(v.x*inv); n.y = f2bf(v.y*inv); n.z = f2bf(v.z*inv); n.w = f2bf(v.w*inv);
    *(ushort4*)(An + ((size_t)b * 2048 + i) * KDIM + lane * 4) = n;
  } else {
    // ---- mlp transpose tile + cb cast, 64x64 per block
    int t = blk - 10240;                // 0..127
    int b = t >> 4, tile = t & 15;
    int dt = (tile >> 2) * 64, wt = (tile & 3) * 64;
    int g  = tid >> 4;                  // 0..15
    int l4 = (tid & 15) * 4;
    const float* mb = mlp + (size_t)b * 256 * 256;
    const float* cs = cb  + (size_t)b * 256 * 256;
    #pragma unroll
    for (int p = 0; p < 4; ++p) {
      int d = dt + p * 16 + g;
      float4 v = *(const float4*)(mb + (size_t)d * 256 + wt + l4);
      lt[p * 16 + g][l4 + 0] = v.x;
      lt[p * 16 + g][l4 + 1] = v.y;
      lt[p * 16 + g][l4 + 2] = v.z;
      lt[p * 16 + g][l4 + 3] = v.w;
      float4 c = *(const float4*)(cs + (size_t)d * 256 + wt + l4);
      ushort4 co;
      co.x = f2bf(c.x); co.y = f2bf(c.y); co.z = f2bf(c.z); co.w = f2bf(c.w);
      *(ushort4*)(cbb + ((size_t)(b * 256 + d)) * 256 + wt + l4) = co;
    }
    __syncthreads();
    #pragma unroll
    for (int p = 0; p < 4; ++p) {
      int w = wt + p * 16 + g;
      ushort4 o;
      o.x = f2bf(lt[l4 + 0][p * 16 + g]);
      o.y = f2bf(lt[l4 + 1][p * 16 + g]);
      o.z = f2bf(lt[l4 + 2][p * 16 + g]);
      o.w = f2bf(lt[l4 + 3][p * 16 + g]);
      *(ushort4*)(mlpT + ((size_t)(b * 256 + w)) * 256 + dt + l4) = o;
    }
  }
}

// ---- fused mid-chain: logits GEMM -> softmax -> out3 -> s GEMM -> s-norm -> An
// one block per (book, 64-row tile): grid = 8*16 = 128, 4 waves.
__global__ __launch_bounds__(256) void mid_kernel(const unsigned short* __restrict__ Xb,
                                                  const unsigned short* __restrict__ mlpT,
                                                  const unsigned short* __restrict__ cbb,
                                                  unsigned short* __restrict__ An,
                                                  float* __restrict__ out3) {
  __shared__ __align__(16) unsigned short lA[64 * 32];     // 4 KB  (x tile)
  __shared__ __align__(16) unsigned short lB[256 * 32];    // 16 KB (B k-slice)
  __shared__ __align__(16) unsigned short lX[64 * 256];    // 32 KB (xc, then sn)

  const int b  = blockIdx.x >> 4;
  const int m0 = (blockIdx.x & 15) * 64;
  const int tid  = threadIdx.x;
  const int wv   = tid >> 6;
  const int lane = tid & 63;
  const int r16  = lane & 15;
  const int q    = lane >> 4;

  const unsigned short* Ab = Xb   + ((size_t)b * NSAMP + m0) * KDIM;
  const unsigned short* Bm = mlpT + (size_t)b * 256 * KDIM;
  const unsigned short* Bc = cbb  + (size_t)b * 256 * KDIM;

  f32x4 acc[16];
  #pragma unroll
  for (int j = 0; j < 16; ++j) acc[j] = (f32x4){0.f, 0.f, 0.f, 0.f};

  // ---------- GEMM1: logits = x @ mlp  (acc[j][r]: row=q*4+r, col=j*16+r16) ----
  for (int k0 = 0; k0 < KDIM; k0 += 32) {
    __syncthreads();                       // prev-iter LDS readers done
    { int row = tid >> 2, ko = (tid & 3) * 8;
      gll16(Ab + (size_t)row * KDIM + k0 + ko, &lA[tid * 8]); }
    #pragma unroll
    for (int c = 0; c < 4; ++c) {
      int idx = c * 256 + tid;
      int row = idx >> 2, ko = (idx & 3) * 8;
      gll16(Bm + (size_t)row * KDIM + k0 + ko, &lB[idx * 8]);
    }
    __syncthreads();                       // compiler drains vmcnt(0) before barrier
    short8 af = *(const short8*)(lA + (wv * 16 + r16) * 32 + q * 8);
    #pragma unroll
    for (int j = 0; j < 16; ++j) {
      short8 bf = *(const short8*)(lB + (j * 16 + r16) * 32 + q * 8);
      acc[j] = __builtin_amdgcn_mfma_f32_16x16x32_bf16(af, bf, acc[j], 0, 0, 0);
    }
  }

  // ---------- softmax over 256 words per row; xc bf16 -> lX (swizzled) --------
  #pragma unroll
  for (int r = 0; r < 4; ++r) {
    float mx = acc[0][r];
    #pragma unroll
    for (int j = 1; j < 16; ++j) mx = fmaxf(mx, acc[j][r]);
    mx = qmax(mx);
    float s = 0.f;
    #pragma unroll
    for (int j = 0; j < 16; ++j) { float e = __expf(acc[j][r] - mx); acc[j][r] = e; s += e; }
    s = qsum(s);
    float inv = 1.f / s;
    int row = wv * 16 + q * 4 + r;
    unsigned rb  = (unsigned)row * 512;
    unsigned msk = ((unsigned)(row & 7)) << 4;
    #pragma unroll
    for (int j = 0; j < 16; ++j) {
      unsigned byte = (rb + (unsigned)(j * 16 + r16) * 2) ^ msk;
      *(unsigned short*)((char*)lX + byte) = f2bf(acc[j][r] * inv);
    }
  }
  __syncthreads();                         // xc visible to all waves

  // ---------- out3 fp32, coalesced from lX (nontemporal: streaming output) ----
  #pragma unroll
  for (int p = 0; p < 8; ++p) {
    int chunk = p * 256 + tid;             // 2048 chunks of 8 elems
    int row = chunk >> 5;
    int c8  = (chunk & 31) * 8;
    unsigned byte = ((unsigned)(row * 512 + c8 * 2)) ^ (((unsigned)(row & 7)) << 4);
    u16x8 v = *(const u16x8*)((char*)lX + byte);
    size_t o = ((size_t)(m0 + row) * 8 + b) * 256 + c8;
    f32x4 f0 = { b2f(v[0]), b2f(v[1]), b2f(v[2]), b2f(v[3]) };
    f32x4 f1 = { b2f(v[4]), b2f(v[5]), b2f(v[6]), b2f(v[7]) };
    __builtin_nontemporal_store(f0, (f32x4*)(out3 + o));
    __builtin_nontemporal_store(f1, (f32x4*)(out3 + o + 4));
  }

  // ---------- GEMM2: s = xc @ cb^T  (A from lX, swizzled reads) ---------------
  #pragma unroll
  for (int j = 0; j < 16; ++j) acc[j] = (f32x4){0.f, 0.f, 0.f, 0.f};
  for (int k0 = 0; k0 < KDIM; k0 += 32) {
    __syncthreads();                       // prev-iter lB readers done
    #pragma unroll
    for (int c = 0; c < 4; ++c) {
      int idx = c * 256 + tid;
      int row = idx >> 2, ko = (idx & 3) * 8;
      gll16(Bc + (size_t)row * KDIM + k0 + ko, &lB[idx * 8]);
    }
    __syncthreads();
    int arow = wv * 16 + r16;
    unsigned abyte = ((unsigned)(arow * 512 + (k0 + q * 8) * 2)) ^ (((unsigned)(arow & 7)) << 4);
    short8 af = *(const short8*)((char*)lX + abyte);
    #pragma unroll
    for (int j = 0; j < 16; ++j) {
      short8 bf = *(const short8*)(lB + (j * 16 + r16) * 32 + q * 8);
      acc[j] = __builtin_amdgcn_mfma_f32_16x16x32_bf16(af, bf, acc[j], 0, 0, 0);
    }
  }

  // ---------- s-normalize in-register; sn bf16 -> lX; coalesced An store ------
  #pragma unroll
  for (int r = 0; r < 4; ++r) {
    float ss = 0.f;
    #pragma unroll
    for (int j = 0; j < 16; ++j) ss += acc[j][r] * acc[j][r];
    ss = qsum(ss);
    float iv = 1.f / fmaxf(sqrtf(ss), 1e-12f);
    int row = wv * 16 + q * 4 + r;
    unsigned rb  = (unsigned)row * 512;
    unsigned msk = ((unsigned)(row & 7)) << 4;
    #pragma unroll
    for (int j = 0; j < 16; ++j) {
      unsigned byte = (rb + (unsigned)(j * 16 + r16) * 2) ^ msk;
      *(unsigned short*)((char*)lX + byte) = f2bf(acc[j][r] * iv);
    }
  }
  __syncthreads();                         // sn visible to all waves
  #pragma unroll
  for (int p = 0; p < 8; ++p) {
    int chunk = p * 256 + tid;
    int row = chunk >> 5;
    int c8  = (chunk & 31) * 8;
    unsigned byte = ((unsigned)(row * 512 + c8 * 2)) ^ (((unsigned)(row & 7)) << 4);
    u16x8 v = *(const u16x8*)((char*)lX + byte);
    *(u16x8*)(An + ((size_t)b * 2048 + 1024 + m0 + row) * KDIM + c8) = v;
  }
}

// ---- big fused GEMM: [xn; sn] (2048xK) @ wn^T (4096xK), global_load_lds staging,
// per-book XCD chunk swizzle (B panel 2MB fits one XCD L2), nontemporal epilogue.
__global__ __launch_bounds__(256) void big_gemm_kernel(const unsigned short* __restrict__ A,
                                                       const unsigned short* __restrict__ B,
                                                       float* __restrict__ Cf,
                                                       const int* __restrict__ label) {
  __shared__ __align__(16) unsigned short lA[128 * 32];
  __shared__ __align__(16) unsigned short lB[128 * 32];

  const int b  = blockIdx.z;
  // bijective XCD chunk swizzle within the 512-block book grid (512 % 8 == 0):
  // XCD k owns wg in [k*64, (k+1)*64) -> 2 m-rows x all n -> B panel stays L2-hot.
  const int lin = blockIdx.x + (blockIdx.y << 5);        // 0..511
  const int wg  = ((lin & 7) << 6) + (lin >> 3);
  const int n0 = (wg & 31) * 128;
  const int m0 = (wg >> 5) * 128;
  const int tid  = threadIdx.x;
  const int wid  = tid >> 6;
  const int lane = tid & 63;
  const int wm = wid & 1, wn = wid >> 1;
  const int r16 = lane & 15;
  const int q   = lane >> 4;

  const unsigned short* Ab = A + (size_t)b * 2048 * KDIM;
  const unsigned short* Bb = B + (size_t)b * OUTF * KDIM;

  f32x4 acc[4][4];
  #pragma unroll
  for (int i = 0; i < 4; ++i)
    #pragma unroll
    for (int j = 0; j < 4; ++j) acc[i][j] = (f32x4){0.f, 0.f, 0.f, 0.f};

  for (int k0 = 0; k0 < KDIM; k0 += 32) {
    __syncthreads();                       // prev-iter LDS readers done
    #pragma unroll
    for (int c = 0; c < 2; ++c) {
      int idx = c * 256 + tid;
      int row = idx >> 2, ko = (idx & 3) * 8;
      gll16(Ab + (size_t)(m0 + row) * KDIM + k0 + ko, &lA[idx * 8]);
      gll16(Bb + (size_t)(n0 + row) * KDIM + k0 + ko, &lB[idx * 8]);
    }
    __syncthreads();                       // vmcnt(0) drained before barrier

    short8 af[4], bfr[4];
    #pragma unroll
    for (int f = 0; f < 4; ++f) {
      af[f]  = *(const short8*)(lA + (wm * 64 + f * 16 + r16) * 32 + q * 8);
      bfr[f] = *(const short8*)(lB + (wn * 64 + f * 16 + r16) * 32 + q * 8);
    }
    #pragma unroll
    for (int i = 0; i < 4; ++i)
      #pragma unroll
      for (int j = 0; j < 4; ++j)
        acc[i][j] = __builtin_amdgcn_mfma_f32_16x16x32_bf16(af[i], bfr[j], acc[i][j], 0, 0, 0);
  }

  // fused epilogue, nontemporal fp32 stores to out[(row>>10)?out2:out1][(i,b,col)]
  #pragma unroll
  for (int i = 0; i < 4; ++i) {
    int row0 = m0 + wm * 64 + i * 16 + q * 4;
    #pragma unroll
    for (int r = 0; r < 4; ++r) {
      int row = row0 + r;                 // 0..2047 within book
      int gi  = row & 1023;               // sample index
      int lb  = label[gi];
      size_t base = (size_t)(row >> 10) * OUT2_OFF + ((size_t)gi * 8 + b) * OUTF;
      #pragma unroll
      for (int j = 0; j < 4; ++j) {
        int col = n0 + wn * 64 + j * 16 + r16;
        float v = fminf(fmaxf(acc[i][j][r], -1.f), 1.f) * 30.f;
        if (col == lb) v -= 15.f;
        __builtin_nontemporal_store(v, &Cf[base + col]);
      }
    }
  }
}

extern "C" void kernel_launch(void* const* d_in, const int* in_sizes, int n_in,
                              void* d_out, int out_size, void* d_ws, size_t ws_size,
                              hipStream_t stream) {
  const float* input  = (const float*)d_in[0];
  const int*   label  = (const int*)d_in[1];
  const float* weight = (const float*)d_in[2];
  const float* mlp    = (const float*)d_in[3];
  const float* cb     = (const float*)d_in[4];
  float* out = (float*)d_out;   // fp32: reference output dtype is float32

  // d_ws: only wn + An (24 MB total)
  unsigned short* wn = (unsigned short*)d_ws;     // 8*4096*256 = 8,388,608 elems (16 MB)
  unsigned short* An = wn + 8388608;              // 8*2048*256 = 4,194,304 elems (8 MB)

  // scratch overlaid on d_out regions written only by the FINAL kernel:
  //   out2 region (134 MB fp32): Xb (raw x bf16), mlpT, cbb — 6 MB
  unsigned short* Xb   = (unsigned short*)(out + OUT2_OFF);    // 2,097,152 bf16 elems
  unsigned short* mlpT = Xb + 2097152;                         //   524,288
  unsigned short* cbb  = mlpT + 524288;                        //   524,288
  float*          out3 = out + OUT3_OFF;

  // merged prep: wnorm (8192 blocks) + xprep (2048) + mlpT/cbb tiles (128)
  prep_kernel<<<dim3(10368), dim3(256), 0, stream>>>(input, weight, mlp, cb,
                                                     wn, Xb, An, mlpT, cbb);
  // fused: logits GEMM -> softmax (-> out3) -> s GEMM -> s-norm -> An rows 1024..2047
  mid_kernel<<<dim3(128), dim3(256), 0, stream>>>(Xb, mlpT, cbb, An, out3);
  // big fused GEMM: [xn; sn] (2048xK) @ wn^T (4096xK) + clip/scale/margin epilogue
  big_gemm_kernel<<<dim3(32, 16, 8), dim3(256), 0, stream>>>(An, wn, out, label);
}

// Round 4
// 365.241 us; speedup vs baseline: 1.1031x; 1.0232x over previous
//
#include <hip/hip_runtime.h>

typedef __attribute__((ext_vector_type(8))) short short8;
typedef __attribute__((ext_vector_type(4))) float f32x4;
typedef __attribute__((ext_vector_type(8))) unsigned short u16x8;

// sizes (fixed by the problem)
#define BOOKS 8
#define NSAMP 1024
#define OUTF  4096
#define KDIM  256
#define OUT2_OFF 33554432ull   // elements in out1 = 1024*8*4096 (fp32 elements)
#define OUT3_OFF 67108864ull

__device__ __forceinline__ unsigned short f2bf(float f) {
  unsigned int u = __float_as_uint(f);
  u += 0x7fffu + ((u >> 16) & 1u);   // round-to-nearest-even
  return (unsigned short)(u >> 16);
}
__device__ __forceinline__ float b2f(unsigned short u) {
  return __uint_as_float((unsigned)u << 16);
}

__device__ __forceinline__ float wave_sum(float v) {
  #pragma unroll
  for (int off = 32; off; off >>= 1) v += __shfl_xor(v, off, 64);
  return v;
}
// 16-lane-group reductions (for MFMA C-layout rows: col = lane&15)
__device__ __forceinline__ float qsum(float v) {
  #pragma unroll
  for (int off = 1; off < 16; off <<= 1) v += __shfl_xor(v, off, 64);
  return v;
}
__device__ __forceinline__ float qmax(float v) {
  #pragma unroll
  for (int off = 1; off < 16; off <<= 1) v = fmaxf(v, __shfl_xor(v, off, 64));
  return v;
}

// async global->LDS, 16B per lane. LDS dest must be wave-uniform base + lane*16.
__device__ __forceinline__ void gll16(const void* g, void* l) {
  __builtin_amdgcn_global_load_lds((const __attribute__((address_space(1))) void*)g,
                                   (__attribute__((address_space(3))) void*)l,
                                   16, 0, 0);
}

// ---- merged prep:
//   blocks [0,8192):      wnorm  (weight rows -> wn bf16, NxK K-contig)
//   blocks [8192,10240):  xprep  (x raw bf16 -> Xb, xn bf16 -> An rows 0..1023)
//   blocks [10240,10368): mlp transpose (LDS-tiled, coalesced both sides) + cb cast
__global__ __launch_bounds__(256) void prep_kernel(const float* __restrict__ input,
                                                   const float* __restrict__ weight,
                                                   const float* __restrict__ mlp,
                                                   const float* __restrict__ cb,
                                                   unsigned short* __restrict__ wn,
                                                   unsigned short* __restrict__ Xb,
                                                   unsigned short* __restrict__ An,
                                                   unsigned short* __restrict__ mlpT,
                                                   unsigned short* __restrict__ cbb) {
  __shared__ float lt[64][65];   // padded f32 transpose tile (2-way bank alias = free)
  const int blk = blockIdx.x;
  const int tid = threadIdx.x;

  if (blk < 8192) {
    // ---- wnorm
    int row  = blk * 4 + (tid >> 6);
    int lane = tid & 63;
    float4 v = ((const float4*)(weight + (size_t)row * KDIM))[lane];
    float ss = wave_sum(v.x*v.x + v.y*v.y + v.z*v.z + v.w*v.w);
    float inv = 1.f / fmaxf(sqrtf(ss), 1e-12f);
    ushort4 o;
    o.x = f2bf(v.x*inv); o.y = f2bf(v.y*inv); o.z = f2bf(v.z*inv); o.w = f2bf(v.w*inv);
    *(ushort4*)(wn + (size_t)row * KDIM + lane * 4) = o;
  } else if (blk < 10240) {
    // ---- xprep
    int id = (blk - 8192) * 4 + (tid >> 6);   // b*1024 + i
    int b = id >> 10, i = id & 1023;
    int lane = tid & 63;
    float4 v = ((const float4*)(input + (size_t)i * 2048 + b * 256))[lane];
    float ss = wave_sum(v.x*v.x + v.y*v.y + v.z*v.z + v.w*v.w);
    float inv = 1.f / fmaxf(sqrtf(ss), 1e-12f);
    ushort4 r;
    r.x = f2bf(v.x); r.y = f2bf(v.y); r.z = f2bf(v.z); r.w = f2bf(v.w);
    *(ushort4*)(Xb + (size_t)id * KDIM + lane * 4) = r;
    ushort4 n;
    n.x = f2bf(v.x*inv); n.y = f2bf(v.y*inv); n.z = f2bf(v.z*inv); n.w = f2bf(v.w*inv);
    *(ushort4*)(An + ((size_t)b * 2048 + i) * KDIM + lane * 4) = n;
  } else {
    // ---- mlp transpose tile + cb cast, 64x64 per block
    int t = blk - 10240;                // 0..127
    int b = t >> 4, tile = t & 15;
    int dt = (tile >> 2) * 64, wt = (tile & 3) * 64;
    int g  = tid >> 4;                  // 0..15
    int l4 = (tid & 15) * 4;
    const float* mb = mlp + (size_t)b * 256 * 256;
    const float* cs = cb  + (size_t)b * 256 * 256;
    #pragma unroll
    for (int p = 0; p < 4; ++p) {
      int d = dt + p * 16 + g;
      float4 v = *(const float4*)(mb + (size_t)d * 256 + wt + l4);
      lt[p * 16 + g][l4 + 0] = v.x;
      lt[p * 16 + g][l4 + 1] = v.y;
      lt[p * 16 + g][l4 + 2] = v.z;
      lt[p * 16 + g][l4 + 3] = v.w;
      float4 c = *(const float4*)(cs + (size_t)d * 256 + wt + l4);
      ushort4 co;
      co.x = f2bf(c.x); co.y = f2bf(c.y); co.z = f2bf(c.z); co.w = f2bf(c.w);
      *(ushort4*)(cbb + ((size_t)(b * 256 + d)) * 256 + wt + l4) = co;
    }
    __syncthreads();
    #pragma unroll
    for (int p = 0; p < 4; ++p) {
      int w = wt + p * 16 + g;
      ushort4 o;
      o.x = f2bf(lt[l4 + 0][p * 16 + g]);
      o.y = f2bf(lt[l4 + 1][p * 16 + g]);
      o.z = f2bf(lt[l4 + 2][p * 16 + g]);
      o.w = f2bf(lt[l4 + 3][p * 16 + g]);
      *(ushort4*)(mlpT + ((size_t)(b * 256 + w)) * 256 + dt + l4) = o;
    }
  }
}

// ---- fused mid-chain v2: logits GEMM -> softmax -> out3 -> s GEMM -> s-norm -> An
// 256 blocks (book, 32-row tile) x 512 threads (8 waves): full device, 2 waves/SIMD.
// wave wid: wm=wid&1 (16-row m-group), wj=wid>>1 (64-col quarter, j=wj*4..wj*4+3).
// Cross-wave row reductions (softmax max/sum, s-norm) via tiny LDS arrays.
__global__ __launch_bounds__(512) void mid_kernel(const unsigned short* __restrict__ Xb,
                                                  const unsigned short* __restrict__ mlpT,
                                                  const unsigned short* __restrict__ cbb,
                                                  unsigned short* __restrict__ An,
                                                  float* __restrict__ out3) {
  __shared__ __align__(16) unsigned short lA[32 * 32];     //  2 KB (x tile)
  __shared__ __align__(16) unsigned short lB[256 * 32];    // 16 KB (B k-slice)
  __shared__ __align__(16) unsigned short lX[32 * 256];    // 16 KB (xc, then sn)
  __shared__ float smx[32][4];   // per-quarter row max
  __shared__ float ssm[32][4];   // per-quarter row expsum
  __shared__ float sqs[32][4];   // per-quarter row sumsq

  const int b  = blockIdx.x >> 5;
  const int m0 = (blockIdx.x & 31) * 32;
  const int tid  = threadIdx.x;
  const int wid  = tid >> 6;
  const int lane = tid & 63;
  const int wm = wid & 1;
  const int wj = wid >> 1;       // 0..3
  const int r16  = lane & 15;
  const int q    = lane >> 4;

  const unsigned short* Ab = Xb   + ((size_t)b * NSAMP + m0) * KDIM;
  const unsigned short* Bm = mlpT + (size_t)b * 256 * KDIM;
  const unsigned short* Bc = cbb  + (size_t)b * 256 * KDIM;

  f32x4 acc[4];
  #pragma unroll
  for (int j = 0; j < 4; ++j) acc[j] = (f32x4){0.f, 0.f, 0.f, 0.f};

  // ---------- GEMM1: logits = x @ mlp  (acc[j][r]: row=q*4+r, col=(wj*4+j)*16+r16)
  for (int k0 = 0; k0 < KDIM; k0 += 32) {
    __syncthreads();                       // prev-iter LDS readers done
    if (tid < 128) {
      int row = tid >> 2, ko = (tid & 3) * 8;
      gll16(Ab + (size_t)row * KDIM + k0 + ko, &lA[tid * 8]);
    }
    #pragma unroll
    for (int c = 0; c < 2; ++c) {
      int idx = c * 512 + tid;
      int row = idx >> 2, ko = (idx & 3) * 8;
      gll16(Bm + (size_t)row * KDIM + k0 + ko, &lB[idx * 8]);
    }
    __syncthreads();                       // compiler drains vmcnt(0) before barrier
    short8 af = *(const short8*)(lA + (wm * 16 + r16) * 32 + q * 8);
    #pragma unroll
    for (int j = 0; j < 4; ++j) {
      short8 bf = *(const short8*)(lB + ((wj * 4 + j) * 16 + r16) * 32 + q * 8);
      acc[j] = __builtin_amdgcn_mfma_f32_16x16x32_bf16(af, bf, acc[j], 0, 0, 0);
    }
  }

  // ---------- softmax over 256 words per row (cross-wave via LDS partials) ----
  #pragma unroll
  for (int r = 0; r < 4; ++r) {
    float mx = fmaxf(fmaxf(acc[0][r], acc[1][r]), fmaxf(acc[2][r], acc[3][r]));
    mx = qmax(mx);
    int rt = wm * 16 + q * 4 + r;
    if (r16 == 0) smx[rt][wj] = mx;
  }
  __syncthreads();
  #pragma unroll
  for (int r = 0; r < 4; ++r) {
    int rt = wm * 16 + q * 4 + r;
    float mx = fmaxf(fmaxf(smx[rt][0], smx[rt][1]), fmaxf(smx[rt][2], smx[rt][3]));
    float s = 0.f;
    #pragma unroll
    for (int j = 0; j < 4; ++j) { float e = __expf(acc[j][r] - mx); acc[j][r] = e; s += e; }
    s = qsum(s);
    if (r16 == 0) ssm[rt][wj] = s;
  }
  __syncthreads();
  #pragma unroll
  for (int r = 0; r < 4; ++r) {
    int rt = wm * 16 + q * 4 + r;
    float inv = 1.f / (ssm[rt][0] + ssm[rt][1] + ssm[rt][2] + ssm[rt][3]);
    unsigned rb  = (unsigned)rt * 512;
    unsigned msk = ((unsigned)(rt & 7)) << 4;
    #pragma unroll
    for (int j = 0; j < 4; ++j) {
      unsigned byte = (rb + (unsigned)((wj * 4 + j) * 16 + r16) * 2) ^ msk;
      *(unsigned short*)((char*)lX + byte) = f2bf(acc[j][r] * inv);
    }
  }
  __syncthreads();                         // xc visible to all waves

  // ---------- out3 fp32, coalesced from lX (nontemporal: streaming output) ----
  #pragma unroll
  for (int p = 0; p < 2; ++p) {
    int chunk = p * 512 + tid;             // 1024 chunks of 8 elems (32 rows x 256)
    int row = chunk >> 5;
    int c8  = (chunk & 31) * 8;
    unsigned byte = ((unsigned)(row * 512 + c8 * 2)) ^ (((unsigned)(row & 7)) << 4);
    u16x8 v = *(const u16x8*)((char*)lX + byte);
    size_t o = ((size_t)(m0 + row) * 8 + b) * 256 + c8;
    f32x4 f0 = { b2f(v[0]), b2f(v[1]), b2f(v[2]), b2f(v[3]) };
    f32x4 f1 = { b2f(v[4]), b2f(v[5]), b2f(v[6]), b2f(v[7]) };
    __builtin_nontemporal_store(f0, (f32x4*)(out3 + o));
    __builtin_nontemporal_store(f1, (f32x4*)(out3 + o + 4));
  }

  // ---------- GEMM2: s = xc @ cb^T  (A from lX, swizzled reads) ---------------
  #pragma unroll
  for (int j = 0; j < 4; ++j) acc[j] = (f32x4){0.f, 0.f, 0.f, 0.f};
  for (int k0 = 0; k0 < KDIM; k0 += 32) {
    __syncthreads();                       // prev-iter lB readers done
    #pragma unroll
    for (int c = 0; c < 2; ++c) {
      int idx = c * 512 + tid;
      int row = idx >> 2, ko = (idx & 3) * 8;
      gll16(Bc + (size_t)row * KDIM + k0 + ko, &lB[idx * 8]);
    }
    __syncthreads();
    int arow = wm * 16 + r16;
    unsigned abyte = ((unsigned)(arow * 512 + (k0 + q * 8) * 2)) ^ (((unsigned)(arow & 7)) << 4);
    short8 af = *(const short8*)((char*)lX + abyte);
    #pragma unroll
    for (int j = 0; j < 4; ++j) {
      short8 bf = *(const short8*)(lB + ((wj * 4 + j) * 16 + r16) * 32 + q * 8);
      acc[j] = __builtin_amdgcn_mfma_f32_16x16x32_bf16(af, bf, acc[j], 0, 0, 0);
    }
  }

  // ---------- s-normalize (cross-wave sumsq); sn bf16 -> lX; An store ---------
  #pragma unroll
  for (int r = 0; r < 4; ++r) {
    float ss = 0.f;
    #pragma unroll
    for (int j = 0; j < 4; ++j) ss += acc[j][r] * acc[j][r];
    ss = qsum(ss);
    int rt = wm * 16 + q * 4 + r;
    if (r16 == 0) sqs[rt][wj] = ss;
  }
  __syncthreads();                         // also: all GEMM2 lX reads done
  #pragma unroll
  for (int r = 0; r < 4; ++r) {
    int rt = wm * 16 + q * 4 + r;
    float tot = sqs[rt][0] + sqs[rt][1] + sqs[rt][2] + sqs[rt][3];
    float iv = 1.f / fmaxf(sqrtf(tot), 1e-12f);
    unsigned rb  = (unsigned)rt * 512;
    unsigned msk = ((unsigned)(rt & 7)) << 4;
    #pragma unroll
    for (int j = 0; j < 4; ++j) {
      unsigned byte = (rb + (unsigned)((wj * 4 + j) * 16 + r16) * 2) ^ msk;
      *(unsigned short*)((char*)lX + byte) = f2bf(acc[j][r] * iv);
    }
  }
  __syncthreads();                         // sn visible to all waves
  #pragma unroll
  for (int p = 0; p < 2; ++p) {
    int chunk = p * 512 + tid;
    int row = chunk >> 5;
    int c8  = (chunk & 31) * 8;
    unsigned byte = ((unsigned)(row * 512 + c8 * 2)) ^ (((unsigned)(row & 7)) << 4);
    u16x8 v = *(const u16x8*)((char*)lX + byte);
    *(u16x8*)(An + ((size_t)b * 2048 + 1024 + m0 + row) * KDIM + c8) = v;
  }
}

// ---- big fused GEMM: [xn; sn] (2048xK) @ wn^T (4096xK), global_load_lds staging,
// plain block mapping (A+B are L3-fit: XCD swizzle costs ~2% per m160 — reverted),
// nontemporal fused epilogue (clip, *30, -15 at label col).
__global__ __launch_bounds__(256) void big_gemm_kernel(const unsigned short* __restrict__ A,
                                                       const unsigned short* __restrict__ B,
                                                       float* __restrict__ Cf,
                                                       const int* __restrict__ label) {
  __shared__ __align__(16) unsigned short lA[128 * 32];
  __shared__ __align__(16) unsigned short lB[128 * 32];

  const int b  = blockIdx.z;
  const int n0 = blockIdx.x * 128;
  const int m0 = blockIdx.y * 128;
  const int tid  = threadIdx.x;
  const int wid  = tid >> 6;
  const int lane = tid & 63;
  const int wm = wid & 1, wn = wid >> 1;
  const int r16 = lane & 15;
  const int q   = lane >> 4;

  const unsigned short* Ab = A + (size_t)b * 2048 * KDIM;
  const unsigned short* Bb = B + (size_t)b * OUTF * KDIM;

  f32x4 acc[4][4];
  #pragma unroll
  for (int i = 0; i < 4; ++i)
    #pragma unroll
    for (int j = 0; j < 4; ++j) acc[i][j] = (f32x4){0.f, 0.f, 0.f, 0.f};

  for (int k0 = 0; k0 < KDIM; k0 += 32) {
    __syncthreads();                       // prev-iter LDS readers done
    #pragma unroll
    for (int c = 0; c < 2; ++c) {
      int idx = c * 256 + tid;
      int row = idx >> 2, ko = (idx & 3) * 8;
      gll16(Ab + (size_t)(m0 + row) * KDIM + k0 + ko, &lA[idx * 8]);
      gll16(Bb + (size_t)(n0 + row) * KDIM + k0 + ko, &lB[idx * 8]);
    }
    __syncthreads();                       // vmcnt(0) drained before barrier

    short8 af[4], bfr[4];
    #pragma unroll
    for (int f = 0; f < 4; ++f) {
      af[f]  = *(const short8*)(lA + (wm * 64 + f * 16 + r16) * 32 + q * 8);
      bfr[f] = *(const short8*)(lB + (wn * 64 + f * 16 + r16) * 32 + q * 8);
    }
    #pragma unroll
    for (int i = 0; i < 4; ++i)
      #pragma unroll
      for (int j = 0; j < 4; ++j)
        acc[i][j] = __builtin_amdgcn_mfma_f32_16x16x32_bf16(af[i], bfr[j], acc[i][j], 0, 0, 0);
  }

  // fused epilogue, nontemporal fp32 stores to out[(row>>10)?out2:out1][(i,b,col)]
  #pragma unroll
  for (int i = 0; i < 4; ++i) {
    int row0 = m0 + wm * 64 + i * 16 + q * 4;
    #pragma unroll
    for (int r = 0; r < 4; ++r) {
      int row = row0 + r;                 // 0..2047 within book
      int gi  = row & 1023;               // sample index
      int lb  = label[gi];
      size_t base = (size_t)(row >> 10) * OUT2_OFF + ((size_t)gi * 8 + b) * OUTF;
      #pragma unroll
      for (int j = 0; j < 4; ++j) {
        int col = n0 + wn * 64 + j * 16 + r16;
        float v = fminf(fmaxf(acc[i][j][r], -1.f), 1.f) * 30.f;
        if (col == lb) v -= 15.f;
        __builtin_nontemporal_store(v, &Cf[base + col]);
      }
    }
  }
}

extern "C" void kernel_launch(void* const* d_in, const int* in_sizes, int n_in,
                              void* d_out, int out_size, void* d_ws, size_t ws_size,
                              hipStream_t stream) {
  const float* input  = (const float*)d_in[0];
  const int*   label  = (const int*)d_in[1];
  const float* weight = (const float*)d_in[2];
  const float* mlp    = (const float*)d_in[3];
  const float* cb     = (const float*)d_in[4];
  float* out = (float*)d_out;   // fp32: reference output dtype is float32

  // d_ws: only wn + An (24 MB total)
  unsigned short* wn = (unsigned short*)d_ws;     // 8*4096*256 = 8,388,608 elems (16 MB)
  unsigned short* An = wn + 8388608;              // 8*2048*256 = 4,194,304 elems (8 MB)

  // scratch overlaid on d_out regions written only by the FINAL kernel:
  //   out2 region (134 MB fp32): Xb (raw x bf16), mlpT, cbb — 6 MB
  unsigned short* Xb   = (unsigned short*)(out + OUT2_OFF);    // 2,097,152 bf16 elems
  unsigned short* mlpT = Xb + 2097152;                         //   524,288
  unsigned short* cbb  = mlpT + 524288;                        //   524,288
  float*          out3 = out + OUT3_OFF;

  // merged prep: wnorm (8192 blocks) + xprep (2048) + mlpT/cbb tiles (128)
  prep_kernel<<<dim3(10368), dim3(256), 0, stream>>>(input, weight, mlp, cb,
                                                     wn, Xb, An, mlpT, cbb);
  // fused: logits GEMM -> softmax (-> out3) -> s GEMM -> s-norm -> An rows 1024..2047
  mid_kernel<<<dim3(256), dim3(512), 0, stream>>>(Xb, mlpT, cbb, An, out3);
  // big fused GEMM: [xn; sn] (2048xK) @ wn^T (4096xK) + clip/scale/margin epilogue
  big_gemm_kernel<<<dim3(32, 16, 8), dim3(256), 0, stream>>>(An, wn, out, label);
}